// Round 2
// baseline (109.066 us; speedup 1.0000x reference)
//
#include <hip/hip_runtime.h>

#define BATCH  65536
#define NIN    9
#define NHID   100
#define TSTEPS 25
#define GSZ    4              // lanes cooperating on one batch element
#define HPT    (NHID / GSZ)   // 25 hidden neurons per lane

// Full-fp64 internal trajectory to bit-track the harness's f64 numpy arbiter.
// One batch element per 4-lane group; each lane owns 25 hidden neurons,
// runs the 25-step LIF recurrence fully unrolled (reset(t+1)==spike(t)),
// accumulating per-step fc2 partials in f64. Butterfly shuffle-reduce
// across the quad, then the mem2 recurrence in f64, store f32.
__global__ __launch_bounds__(256) void snn_kernel(
    const float* __restrict__ x,  const float* __restrict__ W1,
    const float* __restrict__ b1, const float* __restrict__ W2,
    const float* __restrict__ b2, float* __restrict__ out)
{
    __shared__ double sW1[NHID * NIN];   // [h][i], promoted to f64
    __shared__ double sb1[NHID];
    __shared__ double sW2[2 * NHID];     // [o][h]
    __shared__ double sb2[2];

    int tid = threadIdx.x;
    for (int i = tid; i < NHID * NIN; i += 256) sW1[i] = (double)W1[i];
    if (tid < NHID)     sb1[tid] = (double)b1[tid];
    if (tid < 2 * NHID) sW2[tid] = (double)W2[tid];
    if (tid < 2)        sb2[tid] = (double)b2[tid];
    __syncthreads();

    int gtid = blockIdx.x * 256 + tid;
    int b  = gtid >> 2;     // batch element
    int hp = gtid & 3;      // neuron-quarter owned by this lane

    double xv[NIN];
    const float* xp = x + b * NIN;
#pragma unroll
    for (int i = 0; i < NIN; ++i) xv[i] = (double)xp[i];

    // per-step fc2 partial sums (f64)
    double acc0[TSTEPS], acc1[TSTEPS];
#pragma unroll
    for (int t = 0; t < TSTEPS; ++t) { acc0[t] = 0.0; acc1[t] = 0.0; }

    int h0 = hp * HPT;
    for (int j = 0; j < HPT; ++j) {
        int h = h0 + j;
        const double* wr = &sW1[h * NIN];
        double c = 0.0;
#pragma unroll
        for (int i = 0; i < NIN; ++i) c += wr[i] * xv[i];
        c += sb1[h];
        double w0 = sW2[h], w1 = sW2[NHID + h];

        double m = 0.0, s = 0.0;   // s = previous spike == this step's reset
#pragma unroll
        for (int t = 0; t < TSTEPS; ++t) {
            m = 0.95 * m + c - s;              // leaky integrate + subtract-reset
            double sp = (m > 1.0) ? 1.0 : 0.0; // spike
            acc0[t] += sp * w0;
            acc1[t] += sp * w1;
            s = sp;
        }
    }

    // reduce the 4 partial fc2 sums per quad (width-4 butterfly, f64)
#pragma unroll
    for (int t = 0; t < TSTEPS; ++t) {
        double v0 = acc0[t], v1 = acc1[t];
        v0 += __shfl_xor(v0, 1);  v0 += __shfl_xor(v0, 2);
        v1 += __shfl_xor(v1, 1);  v1 += __shfl_xor(v1, 2);
        acc0[t] = v0;  acc1[t] = v1;
    }

    // mem2 recurrence in f64; lane hp==0 stores f32
    if (hp == 0) {
        double m20 = 0.0, m21 = 0.0;
        double bb0 = sb2[0], bb1 = sb2[1];
        float* op = out + (size_t)b * 2;
#pragma unroll
        for (int t = 0; t < TSTEPS; ++t) {
            double r0 = (m20 > 1.0) ? 1.0 : 0.0;
            double r1 = (m21 > 1.0) ? 1.0 : 0.0;
            m20 = 0.95 * m20 + (acc0[t] + bb0) - r0;
            m21 = 0.95 * m21 + (acc1[t] + bb1) - r1;
            *(float2*)(op + (size_t)t * (BATCH * 2)) =
                make_float2((float)m20, (float)m21);
        }
    }
}

extern "C" void kernel_launch(void* const* d_in, const int* in_sizes, int n_in,
                              void* d_out, int out_size, void* d_ws, size_t ws_size,
                              hipStream_t stream) {
    const float* x  = (const float*)d_in[0];
    const float* W1 = (const float*)d_in[1];
    const float* b1 = (const float*)d_in[2];
    const float* W2 = (const float*)d_in[3];
    const float* b2 = (const float*)d_in[4];
    float* out = (float*)d_out;

    dim3 grid((BATCH * GSZ) / 256), block(256);
    hipLaunchKernelGGL(snn_kernel, grid, block, 0, stream, x, W1, b1, W2, b2, out);
}